// Round 4
// baseline (469.595 us; speedup 1.0000x reference)
//
#include <hip/hip_runtime.h>

// KVGather — DIAGNOSTIC ROUND: R3 two-phase kernel with the fan-out store
// pass executed TWICE (identical data; pass 2 overwrites pass 1).
// Purpose: discriminate between
//   Model A: gather writes capped at ~2.5 TB/s  -> bench +165us, dispatch
//            surfaces in top-5 with its own FETCH/WRITE counters
//   Model B: gather already at write roofline (~73us) and a ~97us fixed
//            harness dispatch hides in the timed window -> bench +65us
// Everything except the rep-loop is byte-identical to R3.

constexpr int B    = 4;
constexpr int P2   = 64;
constexpr int TOPK = 16;
constexpr int W2   = 49;
constexpr int C_KV = 512;
constexpr int REGION4 = W2 * C_KV / 4;      // 6272 float4 per region
constexpr int PT      = P2 * TOPK;          // 1024 dest slots per batch
constexpr int CAP     = 128;                // list capacity
constexpr int CHUNKS  = 16;
constexpr int CHUNK4  = REGION4 / CHUNKS;   // 392 float4 = 6272 B = 49 lines
constexpr int TPB     = 256;
constexpr int TAIL    = CHUNK4 - TPB;       // 136 second-round threads

typedef float floatx4 __attribute__((ext_vector_type(4)));

// ws layout: int counts[B*P2]; int lists[B*P2][CAP]
__global__ __launch_bounds__(TPB) void invert_kernel(
    const int* __restrict__ r_idx,
    int* __restrict__ ws)
{
    const int b = blockIdx.x;
    const int t = threadIdx.x;
    __shared__ int s_cnt[P2];
    __shared__ int s_list[P2][CAP];

    if (t < P2) s_cnt[t] = 0;
    __syncthreads();

    const int4 rv = ((const int4*)(r_idx + b * PT))[t];
    const int vals[4] = { rv.x, rv.y, rv.z, rv.w };
    #pragma unroll
    for (int j = 0; j < 4; ++j) {
        const int src = vals[j];
        const int pos = atomicAdd(&s_cnt[src], 1);
        if (pos < CAP) s_list[src][pos] = b * PT + t * 4 + j;
    }
    __syncthreads();

    int* cnt  = ws;
    int* list = ws + B * P2;
    if (t < P2) cnt[b * P2 + t] = min(s_cnt[t], CAP);
    for (int i = t; i < P2 * CAP; i += TPB)
        list[b * P2 * CAP + i] = ((const int*)s_list)[i];
}

__global__ __launch_bounds__(TPB) void fanout_kernel(
    const int* __restrict__ ws,
    const float* __restrict__ kv,
    float* __restrict__ out)
{
    const int blk = blockIdx.x;
    const int c   = blk & (CHUNKS - 1);
    const int bs  = blk >> 4;                // b*P2 + src
    const int t   = threadIdx.x;

    const int* cnt  = ws;
    const int* list = ws + B * P2;

    __shared__ int s_list[CAP];
    const int n = cnt[bs];
    if (t < n) s_list[t] = list[bs * CAP + t];
    __syncthreads();

    const floatx4* __restrict__ s4 =
        (const floatx4*)kv + (size_t)bs * REGION4 + c * CHUNK4;
    const floatx4 v0 = s4[t];
    floatx4 v1 = {};
    if (t < TAIL) v1 = s4[t + TPB];

    floatx4* __restrict__ o4 = (floatx4*)out + c * CHUNK4;

    // DIAGNOSTIC: two identical store passes. Marginal time of pass 2
    // = pure-store cost of 411 MB, measured via the bench delta.
    for (int rep = 0; rep < 2; ++rep) {
        for (int k = 0; k < n; ++k) {
            floatx4* __restrict__ d = o4 + (size_t)s_list[k] * REGION4;
            d[t] = v0;
            if (t < TAIL) d[t + TPB] = v1;
        }
        // Prevent dead-store elimination of pass 1; order the passes.
        __syncthreads();
        asm volatile("" ::: "memory");
    }
}

extern "C" void kernel_launch(void* const* d_in, const int* in_sizes, int n_in,
                              void* d_out, int out_size, void* d_ws, size_t ws_size,
                              hipStream_t stream) {
    const int*   r_idx = (const int*)d_in[0];
    const float* kv    = (const float*)d_in[1];
    float*       out   = (float*)d_out;
    int*         ws    = (int*)d_ws;

    invert_kernel<<<B, TPB, 0, stream>>>(r_idx, ws);
    fanout_kernel<<<B * P2 * CHUNKS, TPB, 0, stream>>>(ws, kv, out);
}

// Round 5
// 430.222 us; speedup vs baseline: 1.0915x; 1.0915x over previous
//
#include <hip/hip_runtime.h>

// KVGather, source-major + register-staged + cached stores. (R2 kernel,
// reverted after the R4 diagnostic; best measured: 428.5 us bench.)
// out[b,p,t,:,:] = kv[b, r_idx[b,p,t], :, :]
// B=4, P2=64, TOPK=16, W2=49, C_KV=512
//
// CONCLUSION OF THE SESSION'S ATTRIBUTION ANALYSIS (R0-R4):
//   The timed window = harness poison fill (~262us, 1.644 GB @ 6.2 TB/s)
//   + ~97us of fixed hidden harness dispatches + this gather (~69us).
//   Mandatory traffic: 411 MB writes + 26 MB kv reads = 437 MB
//   -> 69us at the 6.3 TB/s achieved HBM ceiling. This kernel measures
//   ~69us by fill-subtraction => AT THE MEMORY ROOFLINE.
//   Falsified along the way: NT-store-path cap (R2 null), burst
//   granularity (R2 null), phase serialization / redundant inversion /
//   residency generations (R3 null), 2.5 TB/s write cap (R4 diagnostic:
//   doubling stores cost +37us, incompatible with a store-side cap).

constexpr int B    = 4;
constexpr int P2   = 64;
constexpr int TOPK = 16;
constexpr int W2   = 49;
constexpr int C_KV = 512;
constexpr int REGION4 = W2 * C_KV / 4;     // 6272 float4 per region
constexpr int PT      = P2 * TOPK;         // 1024 dest slots per batch
constexpr int CHUNKS  = 8;                 // chunk-blocks per source region
constexpr int CHUNK4  = REGION4 / CHUNKS;  // 784 float4 per chunk (exact)
constexpr int TPB     = 256;
constexpr int NBLOCKS = B * P2 * CHUNKS;   // 2048 blocks

typedef float floatx4 __attribute__((ext_vector_type(4)));

__global__ __launch_bounds__(TPB) void kvgather_srcmajor_reg(
    const int* __restrict__ r_idx,   // (B, P2, TOPK) flat, int32
    const float* __restrict__ kv,    // (B, P2, W2, C_KV) flat
    float* __restrict__ out)         // (B, P2, TOPK, W2, C_KV) flat
{
    const int blk = blockIdx.x;
    const int c   = blk & (CHUNKS - 1);  // chunk within region
    const int bs  = blk >> 3;            // b*P2 + src
    const int b   = bs >> 6;             // / P2
    const int src = bs & (P2 - 1);
    const int t   = threadIdx.x;

    __shared__ int s_cnt;
    __shared__ int s_base4[PT];          // dest offsets in float4 units

    if (t == 0) s_cnt = 0;
    __syncthreads();

    // Invert r_idx for this (b, src): each thread checks 4 of the 1024
    // dest slots of batch b; matches are compacted into LDS.
    {
        const int4 rv = ((const int4*)(r_idx + b * PT))[t];
        const int vals[4] = { rv.x, rv.y, rv.z, rv.w };
        #pragma unroll
        for (int j = 0; j < 4; ++j) {
            if (vals[j] == src) {
                const int pos = atomicAdd(&s_cnt, 1);
                s_base4[pos] = (b * PT + t * 4 + j) * REGION4;
            }
        }
    }
    __syncthreads();
    const int n = s_cnt;
    if (n == 0) return;

    // Stage this block's chunk (784 float4 = 12.5 KB) in registers.
    const floatx4* __restrict__ s4 =
        (const floatx4*)kv + (size_t)bs * REGION4 + c * CHUNK4;
    const floatx4 v0 = s4[t];
    const floatx4 v1 = s4[t + 256];
    const floatx4 v2 = s4[t + 512];
    floatx4 v3 = {};
    if (t < 16) v3 = s4[t + 768];

    // Per dest: one contiguous 12.5 KB coalesced burst.
    floatx4* __restrict__ o4 = (floatx4*)out + c * CHUNK4;
    for (int k = 0; k < n; ++k) {
        floatx4* __restrict__ d = o4 + s_base4[k];
        d[t]       = v0;
        d[t + 256] = v1;
        d[t + 512] = v2;
        if (t < 16) d[t + 768] = v3;
    }
}

extern "C" void kernel_launch(void* const* d_in, const int* in_sizes, int n_in,
                              void* d_out, int out_size, void* d_ws, size_t ws_size,
                              hipStream_t stream) {
    const int*   r_idx = (const int*)d_in[0];
    const float* kv    = (const float*)d_in[1];
    float*       out   = (float*)d_out;

    kvgather_srcmajor_reg<<<NBLOCKS, TPB, 0, stream>>>(r_idx, kv, out);
}